// Round 6
// baseline (666.712 us; speedup 1.0000x reference)
//
#include <hip/hip_runtime.h>

// GCN: 3x GCNConv(sym-norm, self-loops) + ReLU, mean-pool per graph, FC.
// Strategy: fold dinv into per-layer G = dinv .* (X@W); build dst-CSR once
// per call so aggregation is atomic-free.
// R1: scatter 280us, 194MB WRITE (random 4B writes -> full-line writebacks).
// R2: XCD-blocked scatter -> 170us; WRITE stayed 174MB (read streams evict col).
// R3: nt loads + ILP'd k_agg -> 674us; agg fixed but scatter still 152us/130MB.
// R4: two-pass bucket sort -> 647us; scatter_b fixed (bucket slice L2-resident)
//     but k_bucket's interleaved 8B run-writes re-created the amplification
//     (WRITE 130MB, 164us). Lesson: only contiguous stores kill it.
// R5: k_bucket = LDS tile multisplit. Sort each 1024-edge tile by bucket in
//     LDS (hist -> scan -> place), reserve per-bucket runs, write out sorted
//     -> consecutive addresses, full lines. Edges read once.
//     (R5a: nt-store must go through long long, not int2.)

#define NN 100000
#define EE 3200000
#define FIN 128
#define HID 32
#define NGR 256
#define NC 10
#define NBUK 128
#define BRANGE 782    // 128*782 = 100096 >= NN
#define BSLACK 25800  // mean 25024, sd ~157 -> ~5 sigma slack (input is fixed)
#define SUBB 8        // blocks per bucket in PassB
#define TILE 1024

__global__ void k_init(int* __restrict__ bcur) {
  int t = threadIdx.x;
  if (t < NBUK) bcur[t] = t * BSLACK;
}

__global__ __launch_bounds__(256) void k_dinv(const int* __restrict__ deg,
                                              float* __restrict__ dinv) {
  int n = blockIdx.x * 256 + threadIdx.x;
  if (n < NN) dinv[n] = rsqrtf((float)(deg[n] + 1));  // +1 = self-loop
}

// Pass A: LDS multisplit of one 1024-edge tile into 128 dst-buckets.
// Output writes are sorted-by-bucket -> consecutive global addresses.
__global__ __launch_bounds__(256) void k_bucket(const int* __restrict__ ei,
                                                int* __restrict__ deg,
                                                int* __restrict__ bcur,
                                                long long* __restrict__ bpair) {
  __shared__ int hist[NBUK];   // per-tile bucket counts
  __shared__ int bexc[NBUK];   // exclusive scan of hist
  __shared__ int cnt[NBUK];    // placement cursors
  __shared__ int gofs[NBUK];   // global run offsets
  __shared__ long long sorted[TILE];
  __shared__ int qarr[TILE];
  int t = threadIdx.x;
  const int* src = ei;
  const int* dst = ei + EE;
  int e0 = blockIdx.x * TILE;

  if (t < NBUK) { hist[t] = 0; cnt[t] = 0; }
  __syncthreads();

  int s[4], d[4], q[4];
#pragma unroll
  for (int j = 0; j < 4; j++) {
    int e = e0 + t + j * 256;  // coalesced
    s[j] = __builtin_nontemporal_load(&src[e]);
    d[j] = __builtin_nontemporal_load(&dst[e]);
    q[j] = d[j] / BRANGE;
    atomicAdd(&hist[q[j]], 1);
    atomicAdd(&deg[d[j]], 1);
  }
  __syncthreads();

  // Exclusive scan of hist[0..127] (Hillis-Steele in LDS; all threads sync).
  int hv = 0;
  if (t < NBUK) { hv = hist[t]; bexc[t] = hv; }
  __syncthreads();
#pragma unroll
  for (int off = 1; off < NBUK; off <<= 1) {
    int x = 0;
    if (t < NBUK && t >= off) x = bexc[t - off];
    __syncthreads();
    if (t < NBUK) bexc[t] += x;
    __syncthreads();
  }
  if (t < NBUK) {
    int inc = bexc[t];
    bexc[t] = inc - hv;  // exclusive
    if (hv > 0) gofs[t] = atomicAdd(&bcur[t], hv);
  }
  __syncthreads();

  // Place into sorted LDS array.
#pragma unroll
  for (int j = 0; j < 4; j++) {
    int p = bexc[q[j]] + atomicAdd(&cnt[q[j]], 1);
    sorted[p] = ((long long)(unsigned)d[j] << 32) | (unsigned)s[j];
    qarr[p] = q[j];
  }
  __syncthreads();

  // Write out: consecutive i within a bucket segment -> consecutive global.
  for (int i = t; i < TILE; i += 256) {
    int qq = qarr[i];
    long long pr = sorted[i];
    __builtin_nontemporal_store(pr, &bpair[(size_t)gofs[qq] + (i - bexc[qq])]);
  }
}

// Exclusive scan of deg -> row_ptr (3-kernel hierarchical scan).
__global__ __launch_bounds__(256) void k_scanA(const int* __restrict__ in,
                                               int* __restrict__ out,
                                               int* __restrict__ bsums) {
  __shared__ int tmp[256];
  int t = threadIdx.x;
  int base = blockIdx.x * 1024 + t * 4;
  int v[4];
#pragma unroll
  for (int i = 0; i < 4; i++) v[i] = (base + i < NN) ? in[base + i] : 0;
  int s = v[0] + v[1] + v[2] + v[3];
  tmp[t] = s;
  __syncthreads();
#pragma unroll
  for (int off = 1; off < 256; off <<= 1) {
    int x = (t >= off) ? tmp[t - off] : 0;
    __syncthreads();
    tmp[t] += x;
    __syncthreads();
  }
  int excl = tmp[t] - s;
#pragma unroll
  for (int i = 0; i < 4; i++) {
    if (base + i < NN) out[base + i] = excl;
    excl += v[i];
  }
  if (t == 255) bsums[blockIdx.x] = tmp[255];
}

__global__ void k_scanB(int* __restrict__ bsums, int nb) {
  __shared__ int tmp[256];
  int t = threadIdx.x;
  int v = (t < nb) ? bsums[t] : 0;
  tmp[t] = v;
  __syncthreads();
  for (int off = 1; off < 256; off <<= 1) {
    int x = (t >= off) ? tmp[t - off] : 0;
    __syncthreads();
    tmp[t] += x;
    __syncthreads();
  }
  if (t < nb) bsums[t] = tmp[t] - v;
}

__global__ __launch_bounds__(256) void k_scanC(int* __restrict__ row_ptr,
                                               int* __restrict__ cursor,
                                               const int* __restrict__ bsums) {
  int t = threadIdx.x;
  int base = blockIdx.x * 1024 + t * 4;
  int off = bsums[blockIdx.x];
#pragma unroll
  for (int i = 0; i < 4; i++) {
    int idx = base + i;
    if (idx < NN) {
      int v = row_ptr[idx] + off;
      row_ptr[idx] = v;
      cursor[idx] = v;
    }
  }
  if (blockIdx.x == 0 && t == 0) row_ptr[NN] = EE;
}

// Pass B: scatter within one bucket (100KB col slice, L2-resident).
// bucket = blockIdx&127 keeps XCD affinity (blockIdx&7 == bucket&7).
__global__ __launch_bounds__(256) void k_scatter_b(const long long* __restrict__ bpair,
                                                   const int* __restrict__ bcur,
                                                   int* __restrict__ cursor,
                                                   int* __restrict__ col) {
  int b = blockIdx.x & (NBUK - 1);
  int sub = blockIdx.x >> 7;
  int end = bcur[b];  // end position after PassA
  for (int e = b * BSLACK + sub * 256 + threadIdx.x; e < end; e += SUBB * 256) {
    long long pr = __builtin_nontemporal_load(&bpair[e]);
    int s = (int)(unsigned)(pr & 0xffffffffLL);
    int d = (int)(unsigned)(pr >> 32);
    int pos = atomicAdd(&cursor[d], 1);
    col[pos] = s;
  }
}

// G = dinv .* (X @ W).  128 nodes/block, thread = 4 nodes x 4 feats.
// xs padded to stride 36 floats to break power-of-2 LDS row conflicts.
template <int K>
__global__ __launch_bounds__(256) void k_gemm(const float* __restrict__ X,
                                              const float* __restrict__ W,
                                              const float* __restrict__ dinv,
                                              float* __restrict__ Gout) {
  __shared__ float Wl[K * HID];
  __shared__ float xs[128 * 36];
  int t = threadIdx.x;
  for (int i = t; i < K * HID; i += 256) Wl[i] = W[i];
  int node0 = blockIdx.x * 128;
  int ng = t >> 3, f4 = t & 7;
  float acc[4][4];
#pragma unroll
  for (int j = 0; j < 4; j++)
#pragma unroll
    for (int c = 0; c < 4; c++) acc[j][c] = 0.f;

  for (int kc = 0; kc < K; kc += 32) {
    __syncthreads();
#pragma unroll
    for (int j = 0; j < 4; j++) {
      int idx = t + 256 * j;  // 1024 float4 slots = 128 rows x 8
      int r = idx >> 3, c4 = idx & 7;
      int row = node0 + r;
      if (row >= NN) row = NN - 1;
      float4 v = *reinterpret_cast<const float4*>(&X[(size_t)row * K + kc + c4 * 4]);
      *reinterpret_cast<float4*>(&xs[r * 36 + c4 * 4]) = v;
    }
    __syncthreads();
#pragma unroll
    for (int k4 = 0; k4 < 8; k4++) {
      float4 xv[4];
#pragma unroll
      for (int j = 0; j < 4; j++)
        xv[j] = *reinterpret_cast<const float4*>(&xs[(ng * 4 + j) * 36 + k4 * 4]);
#pragma unroll
      for (int kk = 0; kk < 4; kk++) {
        float4 wv = *reinterpret_cast<const float4*>(&Wl[(kc + k4 * 4 + kk) * HID + f4 * 4]);
#pragma unroll
        for (int j = 0; j < 4; j++) {
          float xvj = (kk == 0) ? xv[j].x : (kk == 1) ? xv[j].y : (kk == 2) ? xv[j].z : xv[j].w;
          acc[j][0] += xvj * wv.x;
          acc[j][1] += xvj * wv.y;
          acc[j][2] += xvj * wv.z;
          acc[j][3] += xvj * wv.w;
        }
      }
    }
  }
#pragma unroll
  for (int j = 0; j < 4; j++) {
    int node = node0 + ng * 4 + j;
    if (node < NN) {
      float s = dinv[node];
      float4 o;
      o.x = acc[j][0] * s;
      o.y = acc[j][1] * s;
      o.z = acc[j][2] * s;
      o.w = acc[j][3] * s;
      *reinterpret_cast<float4*>(&Gout[(size_t)node * HID + f4 * 4]) = o;
    }
  }
}

// X'[n] = act(dinv[n] * (sum_{in-edges} G[src] + G[n]) + b).
// 16 lanes x float2 per node (4 nodes/wave, 16 nodes/block); 8x unrolled
// into 8 independent accumulators for 8 outstanding gathers per slot.
__global__ __launch_bounds__(256) void k_agg(const float* __restrict__ Gin,
                                             const int* __restrict__ col,
                                             const int* __restrict__ row_ptr,
                                             const float* __restrict__ dinv,
                                             const float* __restrict__ bias,
                                             float* __restrict__ Xout, int relu) {
  const float2* G2 = reinterpret_cast<const float2*>(Gin);
  int t = threadIdx.x;
  int h = t & 15;          // float2 index within row (feats 2h, 2h+1)
  int slot = t >> 4;       // 0..15 node slot within block
  int n = blockIdx.x * 16 + slot;
  int beg = row_ptr[n], end = row_ptr[n + 1];

  float2 a0 = G2[(size_t)n * 16 + h];  // self-loop term
  float2 a1 = {0.f, 0.f}, a2 = {0.f, 0.f}, a3 = {0.f, 0.f};
  float2 a4 = {0.f, 0.f}, a5 = {0.f, 0.f}, a6 = {0.f, 0.f}, a7 = {0.f, 0.f};

  int i = beg;
  for (; i + 8 <= end; i += 8) {
    int s0 = __builtin_nontemporal_load(&col[i + 0]);
    int s1 = __builtin_nontemporal_load(&col[i + 1]);
    int s2 = __builtin_nontemporal_load(&col[i + 2]);
    int s3 = __builtin_nontemporal_load(&col[i + 3]);
    int s4 = __builtin_nontemporal_load(&col[i + 4]);
    int s5 = __builtin_nontemporal_load(&col[i + 5]);
    int s6 = __builtin_nontemporal_load(&col[i + 6]);
    int s7 = __builtin_nontemporal_load(&col[i + 7]);
    float2 g0 = G2[(size_t)s0 * 16 + h];
    float2 g1 = G2[(size_t)s1 * 16 + h];
    float2 g2 = G2[(size_t)s2 * 16 + h];
    float2 g3 = G2[(size_t)s3 * 16 + h];
    float2 g4 = G2[(size_t)s4 * 16 + h];
    float2 g5 = G2[(size_t)s5 * 16 + h];
    float2 g6 = G2[(size_t)s6 * 16 + h];
    float2 g7 = G2[(size_t)s7 * 16 + h];
    a0.x += g0.x; a0.y += g0.y;
    a1.x += g1.x; a1.y += g1.y;
    a2.x += g2.x; a2.y += g2.y;
    a3.x += g3.x; a3.y += g3.y;
    a4.x += g4.x; a4.y += g4.y;
    a5.x += g5.x; a5.y += g5.y;
    a6.x += g6.x; a6.y += g6.y;
    a7.x += g7.x; a7.y += g7.y;
  }
  for (; i < end; i++) {
    int s = __builtin_nontemporal_load(&col[i]);
    float2 g = G2[(size_t)s * 16 + h];
    a0.x += g.x; a0.y += g.y;
  }
  a0.x += a1.x + a2.x + a3.x + a4.x + a5.x + a6.x + a7.x;
  a0.y += a1.y + a2.y + a3.y + a4.y + a5.y + a6.y + a7.y;

  float s = dinv[n];
  float2 b = reinterpret_cast<const float2*>(bias)[h];
  float2 v;
  v.x = s * a0.x + b.x;
  v.y = s * a0.y + b.y;
  if (relu) {
    v.x = fmaxf(v.x, 0.f);
    v.y = fmaxf(v.y, 0.f);
  }
  reinterpret_cast<float2*>(Xout)[(size_t)n * 16 + h] = v;
}

// Mean-pool: batch is sorted, so flush-on-graph-change keeps atomics rare.
__global__ __launch_bounds__(256) void k_pool(const float* __restrict__ X,
                                              const int* __restrict__ batch,
                                              float* __restrict__ sums,
                                              int* __restrict__ counts) {
  int t = threadIdx.x;
  int f = t & 31, slot = t >> 5;
  int base = blockIdx.x * 512;
  float acc = 0.f;
  int cnt = 0, cur = -1;
  for (int i = 0; i < 64; i++) {
    int n = base + slot + i * 8;
    if (n >= NN) break;
    int g = batch[n];
    if (g != cur) {
      if (cur >= 0) {
        atomicAdd(&sums[cur * HID + f], acc);
        if (f == 0) atomicAdd(&counts[cur], cnt);
      }
      cur = g;
      acc = 0.f;
      cnt = 0;
    }
    acc += X[(size_t)n * HID + f];
    cnt++;
  }
  if (cur >= 0) {
    atomicAdd(&sums[cur * HID + f], acc);
    if (f == 0) atomicAdd(&counts[cur], cnt);
  }
}

__global__ void k_fc(const float* __restrict__ sums, const int* __restrict__ counts,
                     const float* __restrict__ Wfc, const float* __restrict__ bfc,
                     float* __restrict__ out) {
  int idx = blockIdx.x * 256 + threadIdx.x;
  if (idx >= NGR * NC) return;
  int g = idx / NC, c = idx % NC;
  float inv = 1.f / fmaxf((float)counts[g], 1.f);
  float acc = bfc[c];
#pragma unroll
  for (int k = 0; k < HID; k++) acc += sums[g * HID + k] * inv * Wfc[k * NC + c];
  out[idx] = acc;
}

extern "C" void kernel_launch(void* const* d_in, const int* in_sizes, int n_in,
                              void* d_out, int out_size, void* d_ws, size_t ws_size,
                              hipStream_t stream) {
  (void)in_sizes; (void)n_in; (void)out_size; (void)ws_size;
  const float* x = (const float*)d_in[0];
  const int* ei = (const int*)d_in[1];
  const int* batch = (const int*)d_in[2];
  const float* W1 = (const float*)d_in[3];
  const float* b1 = (const float*)d_in[4];
  const float* W2 = (const float*)d_in[5];
  const float* b2 = (const float*)d_in[6];
  const float* W3 = (const float*)d_in[7];
  const float* b3 = (const float*)d_in[8];
  const float* Wfc = (const float*)d_in[9];
  const float* bfc = (const float*)d_in[10];
  float* out = (float*)d_out;

  char* ws = (char*)d_ws;
  size_t off = 0;
  auto alloc = [&](size_t bytes) -> void* {
    void* p = ws + off;
    off = (off + bytes + 255) & ~(size_t)255;
    return p;
  };
  float* dinv = (float*)alloc((size_t)NN * 4);
  int* deg = (int*)alloc((size_t)NN * 4);
  int* row_ptr = (int*)alloc((size_t)(NN + 1) * 4);
  int* cursor = (int*)alloc((size_t)NN * 4);
  int* bsums = (int*)alloc(256 * 4);
  int* bcur = (int*)alloc(NBUK * 4);
  int* col = (int*)alloc((size_t)EE * 4);
  // Union region: bpair (PassA/B only) overlaps Gbuf+Abuf (GEMM phase only).
  size_t bpair_bytes = (size_t)NBUK * BSLACK * 8;       // 26.4 MB
  size_t gbuf_bytes = (size_t)NN * HID * 4;             // 12.8 MB
  char* uni = (char*)alloc(bpair_bytes > 2 * gbuf_bytes ? bpair_bytes : 2 * gbuf_bytes);
  long long* bpair = (long long*)uni;
  float* Gbuf = (float*)uni;
  float* Abuf = (float*)(uni + gbuf_bytes);
  float* sums = (float*)alloc((size_t)NGR * HID * 4);
  int* counts = (int*)alloc((size_t)NGR * 4);

  hipMemsetAsync(deg, 0, (size_t)NN * 4, stream);
  hipMemsetAsync(sums, 0, (size_t)NGR * HID * 4, stream);
  hipMemsetAsync(counts, 0, (size_t)NGR * 4, stream);

  k_init<<<1, NBUK, 0, stream>>>(bcur);
  k_bucket<<<EE / TILE, 256, 0, stream>>>(ei, deg, bcur, bpair);  // 3125 blocks
  k_dinv<<<(NN + 255) / 256, 256, 0, stream>>>(deg, dinv);
  int nb = (NN + 1023) / 1024;  // 98
  k_scanA<<<nb, 256, 0, stream>>>(deg, row_ptr, bsums);
  k_scanB<<<1, 256, 0, stream>>>(bsums, nb);
  k_scanC<<<nb, 256, 0, stream>>>(row_ptr, cursor, bsums);
  k_scatter_b<<<NBUK * SUBB, 256, 0, stream>>>(bpair, bcur, cursor, col);

  k_gemm<FIN><<<(NN + 127) / 128, 256, 0, stream>>>(x, W1, dinv, Gbuf);
  k_agg<<<NN / 16, 256, 0, stream>>>(Gbuf, col, row_ptr, dinv, b1, Abuf, 1);
  k_gemm<HID><<<(NN + 127) / 128, 256, 0, stream>>>(Abuf, W2, dinv, Gbuf);
  k_agg<<<NN / 16, 256, 0, stream>>>(Gbuf, col, row_ptr, dinv, b2, Abuf, 1);
  k_gemm<HID><<<(NN + 127) / 128, 256, 0, stream>>>(Abuf, W3, dinv, Gbuf);
  k_agg<<<NN / 16, 256, 0, stream>>>(Gbuf, col, row_ptr, dinv, b3, Abuf, 0);

  k_pool<<<(NN + 511) / 512, 256, 0, stream>>>(Abuf, batch, sums, counts);
  k_fc<<<(NGR * NC + 255) / 256, 256, 0, stream>>>(sums, counts, Wfc, bfc, out);
}

// Round 7
// 630.292 us; speedup vs baseline: 1.0578x; 1.0578x over previous
//
#include <hip/hip_runtime.h>

// GCN: 3x GCNConv(sym-norm, self-loops) + ReLU, mean-pool per graph, FC.
// Strategy: fold dinv into per-layer G = dinv .* (X@W); build dst-CSR once
// per call so aggregation is atomic-free.
// R1: scatter 280us, 194MB WRITE (random 4B writes -> full-line writebacks).
// R2: XCD-blocked scatter -> 170us; WRITE stayed 174MB (read streams evict col).
// R3: nt loads + ILP'd k_agg -> 674us; agg fixed but scatter still 152us/130MB.
// R4: two-pass bucket sort -> 647us; k_bucket's interleaved 8B run-writes
//     re-created the amplification (WRITE 130MB).
// R5/R6: LDS multisplit TILE=1024 -> WRITE still 135MB: 64B runs start
//     unaligned and the completing neighbor-run comes from another block/XCD
//     later -> partial-line eviction. Lesson: per-block bucket-runs must be
//     multiple cache lines.
// R7: TILE=8192 (runs ~512B -> ~1.2x amplification). Two read passes per
//     block (regs can't hold 32 edges); pass 2 hits L2. No qarr (recompute
//     q from packed dst) so sorted[8192] = 64KB fits, 2 blocks/CU.

#define NN 100000
#define EE 3200000
#define FIN 128
#define HID 32
#define NGR 256
#define NC 10
#define NBUK 128
#define BRANGE 782    // 128*782 = 100096 >= NN
#define BSLACK 25800  // mean 25024, sd ~157 -> ~5 sigma slack (input is fixed)
#define SUBB 8        // blocks per bucket in PassB
#define TILE 8192

__global__ void k_init(int* __restrict__ bcur) {
  int t = threadIdx.x;
  if (t < NBUK) bcur[t] = t * BSLACK;
}

__global__ __launch_bounds__(256) void k_dinv(const int* __restrict__ deg,
                                              float* __restrict__ dinv) {
  int n = blockIdx.x * 256 + threadIdx.x;
  if (n < NN) dinv[n] = rsqrtf((float)(deg[n] + 1));  // +1 = self-loop
}

// Pass A: LDS multisplit of one 8192-edge tile into 128 dst-buckets.
// Pass 1 histograms (fused deg count); pass 2 re-reads (L2-hit) and places
// into sorted LDS; write-out is bucket-contiguous -> ~512B runs, full lines.
__global__ __launch_bounds__(256) void k_bucket(const int* __restrict__ ei,
                                                int* __restrict__ deg,
                                                int* __restrict__ bcur,
                                                long long* __restrict__ bpair) {
  __shared__ int hist[NBUK];          // per-tile bucket counts
  __shared__ int bexc[NBUK];          // exclusive scan of hist
  __shared__ int cnt[NBUK];           // placement cursors
  __shared__ int gofs[NBUK];          // global run offsets
  __shared__ long long sorted[TILE];  // 64 KB
  int t = threadIdx.x;
  const int* src = ei;
  const int* dst = ei + EE;
  int e0 = blockIdx.x * TILE;
  int tn = EE - e0;
  if (tn > TILE) tn = TILE;

  if (t < NBUK) { hist[t] = 0; cnt[t] = 0; }
  __syncthreads();

  // Pass 1: histogram + global deg count.
  for (int i = t; i < tn; i += 256) {
    int d = __builtin_nontemporal_load(&dst[e0 + i]);
    atomicAdd(&hist[d / BRANGE], 1);
    atomicAdd(&deg[d], 1);
  }
  __syncthreads();

  // Exclusive scan of hist[0..127] (Hillis-Steele in LDS; all threads sync).
  int hv = 0;
  if (t < NBUK) { hv = hist[t]; bexc[t] = hv; }
  __syncthreads();
#pragma unroll
  for (int off = 1; off < NBUK; off <<= 1) {
    int x = 0;
    if (t < NBUK && t >= off) x = bexc[t - off];
    __syncthreads();
    if (t < NBUK) bexc[t] += x;
    __syncthreads();
  }
  if (t < NBUK) {
    int inc = bexc[t];
    bexc[t] = inc - hv;  // exclusive
    if (hv > 0) gofs[t] = atomicAdd(&bcur[t], hv);
  }
  __syncthreads();

  // Pass 2: re-read (L2-hit) and place into sorted LDS array.
  for (int i = t; i < tn; i += 256) {
    int d = dst[e0 + i];
    int s = src[e0 + i];
    int q = d / BRANGE;
    int p = bexc[q] + atomicAdd(&cnt[q], 1);
    sorted[p] = ((long long)(unsigned)d << 32) | (unsigned)s;
  }
  __syncthreads();

  // Write out: consecutive i within a bucket segment -> consecutive global.
  for (int i = t; i < tn; i += 256) {
    long long pr = sorted[i];
    int q = (int)(unsigned)(pr >> 32) / BRANGE;
    __builtin_nontemporal_store(pr, &bpair[(size_t)gofs[q] + (i - bexc[q])]);
  }
}

// Exclusive scan of deg -> row_ptr (3-kernel hierarchical scan).
__global__ __launch_bounds__(256) void k_scanA(const int* __restrict__ in,
                                               int* __restrict__ out,
                                               int* __restrict__ bsums) {
  __shared__ int tmp[256];
  int t = threadIdx.x;
  int base = blockIdx.x * 1024 + t * 4;
  int v[4];
#pragma unroll
  for (int i = 0; i < 4; i++) v[i] = (base + i < NN) ? in[base + i] : 0;
  int s = v[0] + v[1] + v[2] + v[3];
  tmp[t] = s;
  __syncthreads();
#pragma unroll
  for (int off = 1; off < 256; off <<= 1) {
    int x = (t >= off) ? tmp[t - off] : 0;
    __syncthreads();
    tmp[t] += x;
    __syncthreads();
  }
  int excl = tmp[t] - s;
#pragma unroll
  for (int i = 0; i < 4; i++) {
    if (base + i < NN) out[base + i] = excl;
    excl += v[i];
  }
  if (t == 255) bsums[blockIdx.x] = tmp[255];
}

__global__ void k_scanB(int* __restrict__ bsums, int nb) {
  __shared__ int tmp[256];
  int t = threadIdx.x;
  int v = (t < nb) ? bsums[t] : 0;
  tmp[t] = v;
  __syncthreads();
  for (int off = 1; off < 256; off <<= 1) {
    int x = (t >= off) ? tmp[t - off] : 0;
    __syncthreads();
    tmp[t] += x;
    __syncthreads();
  }
  if (t < nb) bsums[t] = tmp[t] - v;
}

__global__ __launch_bounds__(256) void k_scanC(int* __restrict__ row_ptr,
                                               int* __restrict__ cursor,
                                               const int* __restrict__ bsums) {
  int t = threadIdx.x;
  int base = blockIdx.x * 1024 + t * 4;
  int off = bsums[blockIdx.x];
#pragma unroll
  for (int i = 0; i < 4; i++) {
    int idx = base + i;
    if (idx < NN) {
      int v = row_ptr[idx] + off;
      row_ptr[idx] = v;
      cursor[idx] = v;
    }
  }
  if (blockIdx.x == 0 && t == 0) row_ptr[NN] = EE;
}

// Pass B: scatter within one bucket (100KB col slice, L2-resident).
// bucket = blockIdx&127 keeps XCD affinity (blockIdx&7 == bucket&7).
__global__ __launch_bounds__(256) void k_scatter_b(const long long* __restrict__ bpair,
                                                   const int* __restrict__ bcur,
                                                   int* __restrict__ cursor,
                                                   int* __restrict__ col) {
  int b = blockIdx.x & (NBUK - 1);
  int sub = blockIdx.x >> 7;
  int end = bcur[b];  // end position after PassA
  for (int e = b * BSLACK + sub * 256 + threadIdx.x; e < end; e += SUBB * 256) {
    long long pr = __builtin_nontemporal_load(&bpair[e]);
    int s = (int)(unsigned)(pr & 0xffffffffLL);
    int d = (int)(unsigned)(pr >> 32);
    int pos = atomicAdd(&cursor[d], 1);
    col[pos] = s;
  }
}

// G = dinv .* (X @ W).  128 nodes/block, thread = 4 nodes x 4 feats.
// xs padded to stride 36 floats to break power-of-2 LDS row conflicts.
template <int K>
__global__ __launch_bounds__(256) void k_gemm(const float* __restrict__ X,
                                              const float* __restrict__ W,
                                              const float* __restrict__ dinv,
                                              float* __restrict__ Gout) {
  __shared__ float Wl[K * HID];
  __shared__ float xs[128 * 36];
  int t = threadIdx.x;
  for (int i = t; i < K * HID; i += 256) Wl[i] = W[i];
  int node0 = blockIdx.x * 128;
  int ng = t >> 3, f4 = t & 7;
  float acc[4][4];
#pragma unroll
  for (int j = 0; j < 4; j++)
#pragma unroll
    for (int c = 0; c < 4; c++) acc[j][c] = 0.f;

  for (int kc = 0; kc < K; kc += 32) {
    __syncthreads();
#pragma unroll
    for (int j = 0; j < 4; j++) {
      int idx = t + 256 * j;  // 1024 float4 slots = 128 rows x 8
      int r = idx >> 3, c4 = idx & 7;
      int row = node0 + r;
      if (row >= NN) row = NN - 1;
      float4 v = *reinterpret_cast<const float4*>(&X[(size_t)row * K + kc + c4 * 4]);
      *reinterpret_cast<float4*>(&xs[r * 36 + c4 * 4]) = v;
    }
    __syncthreads();
#pragma unroll
    for (int k4 = 0; k4 < 8; k4++) {
      float4 xv[4];
#pragma unroll
      for (int j = 0; j < 4; j++)
        xv[j] = *reinterpret_cast<const float4*>(&xs[(ng * 4 + j) * 36 + k4 * 4]);
#pragma unroll
      for (int kk = 0; kk < 4; kk++) {
        float4 wv = *reinterpret_cast<const float4*>(&Wl[(kc + k4 * 4 + kk) * HID + f4 * 4]);
#pragma unroll
        for (int j = 0; j < 4; j++) {
          float xvj = (kk == 0) ? xv[j].x : (kk == 1) ? xv[j].y : (kk == 2) ? xv[j].z : xv[j].w;
          acc[j][0] += xvj * wv.x;
          acc[j][1] += xvj * wv.y;
          acc[j][2] += xvj * wv.z;
          acc[j][3] += xvj * wv.w;
        }
      }
    }
  }
#pragma unroll
  for (int j = 0; j < 4; j++) {
    int node = node0 + ng * 4 + j;
    if (node < NN) {
      float s = dinv[node];
      float4 o;
      o.x = acc[j][0] * s;
      o.y = acc[j][1] * s;
      o.z = acc[j][2] * s;
      o.w = acc[j][3] * s;
      *reinterpret_cast<float4*>(&Gout[(size_t)node * HID + f4 * 4]) = o;
    }
  }
}

// X'[n] = act(dinv[n] * (sum_{in-edges} G[src] + G[n]) + b).
// 16 lanes x float2 per node (4 nodes/wave, 16 nodes/block); 8x unrolled
// into 8 independent accumulators for 8 outstanding gathers per slot.
__global__ __launch_bounds__(256) void k_agg(const float* __restrict__ Gin,
                                             const int* __restrict__ col,
                                             const int* __restrict__ row_ptr,
                                             const float* __restrict__ dinv,
                                             const float* __restrict__ bias,
                                             float* __restrict__ Xout, int relu) {
  const float2* G2 = reinterpret_cast<const float2*>(Gin);
  int t = threadIdx.x;
  int h = t & 15;          // float2 index within row (feats 2h, 2h+1)
  int slot = t >> 4;       // 0..15 node slot within block
  int n = blockIdx.x * 16 + slot;
  int beg = row_ptr[n], end = row_ptr[n + 1];

  float2 a0 = G2[(size_t)n * 16 + h];  // self-loop term
  float2 a1 = {0.f, 0.f}, a2 = {0.f, 0.f}, a3 = {0.f, 0.f};
  float2 a4 = {0.f, 0.f}, a5 = {0.f, 0.f}, a6 = {0.f, 0.f}, a7 = {0.f, 0.f};

  int i = beg;
  for (; i + 8 <= end; i += 8) {
    int s0 = __builtin_nontemporal_load(&col[i + 0]);
    int s1 = __builtin_nontemporal_load(&col[i + 1]);
    int s2 = __builtin_nontemporal_load(&col[i + 2]);
    int s3 = __builtin_nontemporal_load(&col[i + 3]);
    int s4 = __builtin_nontemporal_load(&col[i + 4]);
    int s5 = __builtin_nontemporal_load(&col[i + 5]);
    int s6 = __builtin_nontemporal_load(&col[i + 6]);
    int s7 = __builtin_nontemporal_load(&col[i + 7]);
    float2 g0 = G2[(size_t)s0 * 16 + h];
    float2 g1 = G2[(size_t)s1 * 16 + h];
    float2 g2 = G2[(size_t)s2 * 16 + h];
    float2 g3 = G2[(size_t)s3 * 16 + h];
    float2 g4 = G2[(size_t)s4 * 16 + h];
    float2 g5 = G2[(size_t)s5 * 16 + h];
    float2 g6 = G2[(size_t)s6 * 16 + h];
    float2 g7 = G2[(size_t)s7 * 16 + h];
    a0.x += g0.x; a0.y += g0.y;
    a1.x += g1.x; a1.y += g1.y;
    a2.x += g2.x; a2.y += g2.y;
    a3.x += g3.x; a3.y += g3.y;
    a4.x += g4.x; a4.y += g4.y;
    a5.x += g5.x; a5.y += g5.y;
    a6.x += g6.x; a6.y += g6.y;
    a7.x += g7.x; a7.y += g7.y;
  }
  for (; i < end; i++) {
    int s = __builtin_nontemporal_load(&col[i]);
    float2 g = G2[(size_t)s * 16 + h];
    a0.x += g.x; a0.y += g.y;
  }
  a0.x += a1.x + a2.x + a3.x + a4.x + a5.x + a6.x + a7.x;
  a0.y += a1.y + a2.y + a3.y + a4.y + a5.y + a6.y + a7.y;

  float s = dinv[n];
  float2 b = reinterpret_cast<const float2*>(bias)[h];
  float2 v;
  v.x = s * a0.x + b.x;
  v.y = s * a0.y + b.y;
  if (relu) {
    v.x = fmaxf(v.x, 0.f);
    v.y = fmaxf(v.y, 0.f);
  }
  reinterpret_cast<float2*>(Xout)[(size_t)n * 16 + h] = v;
}

// Mean-pool: batch is sorted, so flush-on-graph-change keeps atomics rare.
__global__ __launch_bounds__(256) void k_pool(const float* __restrict__ X,
                                              const int* __restrict__ batch,
                                              float* __restrict__ sums,
                                              int* __restrict__ counts) {
  int t = threadIdx.x;
  int f = t & 31, slot = t >> 5;
  int base = blockIdx.x * 512;
  float acc = 0.f;
  int cnt = 0, cur = -1;
  for (int i = 0; i < 64; i++) {
    int n = base + slot + i * 8;
    if (n >= NN) break;
    int g = batch[n];
    if (g != cur) {
      if (cur >= 0) {
        atomicAdd(&sums[cur * HID + f], acc);
        if (f == 0) atomicAdd(&counts[cur], cnt);
      }
      cur = g;
      acc = 0.f;
      cnt = 0;
    }
    acc += X[(size_t)n * HID + f];
    cnt++;
  }
  if (cur >= 0) {
    atomicAdd(&sums[cur * HID + f], acc);
    if (f == 0) atomicAdd(&counts[cur], cnt);
  }
}

__global__ void k_fc(const float* __restrict__ sums, const int* __restrict__ counts,
                     const float* __restrict__ Wfc, const float* __restrict__ bfc,
                     float* __restrict__ out) {
  int idx = blockIdx.x * 256 + threadIdx.x;
  if (idx >= NGR * NC) return;
  int g = idx / NC, c = idx % NC;
  float inv = 1.f / fmaxf((float)counts[g], 1.f);
  float acc = bfc[c];
#pragma unroll
  for (int k = 0; k < HID; k++) acc += sums[g * HID + k] * inv * Wfc[k * NC + c];
  out[idx] = acc;
}

extern "C" void kernel_launch(void* const* d_in, const int* in_sizes, int n_in,
                              void* d_out, int out_size, void* d_ws, size_t ws_size,
                              hipStream_t stream) {
  (void)in_sizes; (void)n_in; (void)out_size; (void)ws_size;
  const float* x = (const float*)d_in[0];
  const int* ei = (const int*)d_in[1];
  const int* batch = (const int*)d_in[2];
  const float* W1 = (const float*)d_in[3];
  const float* b1 = (const float*)d_in[4];
  const float* W2 = (const float*)d_in[5];
  const float* b2 = (const float*)d_in[6];
  const float* W3 = (const float*)d_in[7];
  const float* b3 = (const float*)d_in[8];
  const float* Wfc = (const float*)d_in[9];
  const float* bfc = (const float*)d_in[10];
  float* out = (float*)d_out;

  char* ws = (char*)d_ws;
  size_t off = 0;
  auto alloc = [&](size_t bytes) -> void* {
    void* p = ws + off;
    off = (off + bytes + 255) & ~(size_t)255;
    return p;
  };
  float* dinv = (float*)alloc((size_t)NN * 4);
  int* deg = (int*)alloc((size_t)NN * 4);
  int* row_ptr = (int*)alloc((size_t)(NN + 1) * 4);
  int* cursor = (int*)alloc((size_t)NN * 4);
  int* bsums = (int*)alloc(256 * 4);
  int* bcur = (int*)alloc(NBUK * 4);
  int* col = (int*)alloc((size_t)EE * 4);
  // Union region: bpair (PassA/B only) overlaps Gbuf+Abuf (GEMM phase only).
  size_t bpair_bytes = (size_t)NBUK * BSLACK * 8;       // 26.4 MB
  size_t gbuf_bytes = (size_t)NN * HID * 4;             // 12.8 MB
  char* uni = (char*)alloc(bpair_bytes > 2 * gbuf_bytes ? bpair_bytes : 2 * gbuf_bytes);
  long long* bpair = (long long*)uni;
  float* Gbuf = (float*)uni;
  float* Abuf = (float*)(uni + gbuf_bytes);
  float* sums = (float*)alloc((size_t)NGR * HID * 4);
  int* counts = (int*)alloc((size_t)NGR * 4);

  hipMemsetAsync(deg, 0, (size_t)NN * 4, stream);
  hipMemsetAsync(sums, 0, (size_t)NGR * HID * 4, stream);
  hipMemsetAsync(counts, 0, (size_t)NGR * 4, stream);

  k_init<<<1, NBUK, 0, stream>>>(bcur);
  k_bucket<<<(EE + TILE - 1) / TILE, 256, 0, stream>>>(ei, deg, bcur, bpair);  // 391 blocks
  k_dinv<<<(NN + 255) / 256, 256, 0, stream>>>(deg, dinv);
  int nb = (NN + 1023) / 1024;  // 98
  k_scanA<<<nb, 256, 0, stream>>>(deg, row_ptr, bsums);
  k_scanB<<<1, 256, 0, stream>>>(bsums, nb);
  k_scanC<<<nb, 256, 0, stream>>>(row_ptr, cursor, bsums);
  k_scatter_b<<<NBUK * SUBB, 256, 0, stream>>>(bpair, bcur, cursor, col);

  k_gemm<FIN><<<(NN + 127) / 128, 256, 0, stream>>>(x, W1, dinv, Gbuf);
  k_agg<<<NN / 16, 256, 0, stream>>>(Gbuf, col, row_ptr, dinv, b1, Abuf, 1);
  k_gemm<HID><<<(NN + 127) / 128, 256, 0, stream>>>(Abuf, W2, dinv, Gbuf);
  k_agg<<<NN / 16, 256, 0, stream>>>(Gbuf, col, row_ptr, dinv, b2, Abuf, 1);
  k_gemm<HID><<<(NN + 127) / 128, 256, 0, stream>>>(Abuf, W3, dinv, Gbuf);
  k_agg<<<NN / 16, 256, 0, stream>>>(Gbuf, col, row_ptr, dinv, b3, Abuf, 0);

  k_pool<<<(NN + 511) / 512, 256, 0, stream>>>(Abuf, batch, sums, counts);
  k_fc<<<(NGR * NC + 255) / 256, 256, 0, stream>>>(sums, counts, Wfc, bfc, out);
}

// Round 8
// 480.394 us; speedup vs baseline: 1.3878x; 1.3120x over previous
//
#include <hip/hip_runtime.h>

// GCN: 3x GCNConv(sym-norm, self-loops) + ReLU, mean-pool per graph, FC.
// Strategy: fold dinv into per-layer G = dinv .* (X@W); build dst-CSR once
// per call so aggregation is atomic-free.
// R1-R7 history: chased store-coalescing for 6 rounds (XCD blocking, nt hints,
//   bucket sort, LDS multisplit 1K/8K tiles). R7 falsified that model: WRITE
//   stayed ~130MB with perfectly coalesced 512B runs. Re-fit across rounds:
//   WRITE ~= 32B x (# global no-return atomics) + true stores. Every 4B
//   device-scope atomic costs ~32B fabric write traffic and they are also the
//   latency bound (~25G atomics/s, VALU 2%, HBM 11%).
// R8: eliminate global atomics from the hot path. k_bucket drops the deg
//   atomic (only ~65K bcur reservations remain). New fused k_place: one block
//   per bucket, LDS histogram + LDS scan + LDS cursors -> writes dinv,
//   row_ptr coalesced and col within the block's own ~50KB window with ZERO
//   global atomics. Deletes k_count/k_dinv/scanA/B/C/k_scatter_b.

#define NN 100000
#define EE 3200000
#define FIN 128
#define HID 32
#define NGR 256
#define NC 10
#define NBUK 256
#define BRANGE 391    // 256*391 = 100096 >= NN
#define BSLACK 13400  // mean 12500, sd ~112 -> ~8 sigma slack (input is fixed)
#define TILE 8192

__global__ void k_init(int* __restrict__ bcur) {
  int t = threadIdx.x;
  if (t < NBUK) bcur[t] = t * BSLACK;
}

// Pass A: LDS multisplit of one 8192-edge tile into 256 dst-buckets.
// Pass 1 histograms dst; pass 2 re-reads (L2/L3-hit) and places into sorted
// LDS; write-out is bucket-contiguous (~256B runs). No per-edge global atomics.
__global__ __launch_bounds__(256) void k_bucket(const int* __restrict__ ei,
                                                int* __restrict__ bcur,
                                                long long* __restrict__ bpair) {
  __shared__ int hist[NBUK];          // per-tile bucket counts
  __shared__ int bexc[NBUK];          // exclusive scan of hist
  __shared__ int cnt[NBUK];           // placement cursors
  __shared__ int gofs[NBUK];          // global run offsets
  __shared__ long long sorted[TILE];  // 64 KB
  int t = threadIdx.x;
  const int* src = ei;
  const int* dst = ei + EE;
  int e0 = blockIdx.x * TILE;
  int tn = EE - e0;
  if (tn > TILE) tn = TILE;

  hist[t] = 0;
  cnt[t] = 0;
  __syncthreads();

  // Pass 1: histogram of dst-buckets (LDS atomics only).
  for (int i = t; i < tn; i += 256) {
    int d = __builtin_nontemporal_load(&dst[e0 + i]);
    atomicAdd(&hist[d / BRANGE], 1);
  }
  __syncthreads();

  // Exclusive scan of hist[0..255] (Hillis-Steele, all 256 threads).
  int hv = hist[t];
  bexc[t] = hv;
  __syncthreads();
#pragma unroll
  for (int off = 1; off < NBUK; off <<= 1) {
    int x = (t >= off) ? bexc[t - off] : 0;
    __syncthreads();
    bexc[t] += x;
    __syncthreads();
  }
  {
    int inc = bexc[t];
    bexc[t] = inc - hv;  // exclusive
    if (hv > 0) gofs[t] = atomicAdd(&bcur[t], hv);  // ~65K atomics total
  }
  __syncthreads();

  // Pass 2: re-read (cache-hit) and place into sorted LDS array.
  for (int i = t; i < tn; i += 256) {
    int d = dst[e0 + i];
    int s = src[e0 + i];
    int q = d / BRANGE;
    int p = bexc[q] + atomicAdd(&cnt[q], 1);
    sorted[p] = ((long long)(unsigned)d << 32) | (unsigned)s;
  }
  __syncthreads();

  // Write out: consecutive i within a bucket segment -> consecutive global.
  for (int i = t; i < tn; i += 256) {
    long long pr = sorted[i];
    int q = (int)(unsigned)(pr >> 32) / BRANGE;
    __builtin_nontemporal_store(pr, &bpair[(size_t)gofs[q] + (i - bexc[q])]);
  }
}

// Fused CSR finalize: one block per bucket. LDS histogram of the bucket's
// ~12.5K pairs -> in-block scan -> write dinv + row_ptr coalesced -> place
// col via LDS cursors. Zero global atomics; col writes land in this block's
// own ~50KB contiguous window.
__global__ __launch_bounds__(256) void k_place(const long long* __restrict__ bpair,
                                               const int* __restrict__ bcur,
                                               float* __restrict__ dinv,
                                               int* __restrict__ row_ptr,
                                               int* __restrict__ col) {
  __shared__ int bs[NBUK];     // bucket sizes -> inclusive scan -> col bases
  __shared__ int cnt[BRANGE];  // per-node counts -> absolute cursors
  __shared__ int thsum[256];
  int b = blockIdx.x, t = threadIdx.x;

  bs[t] = bcur[t] - t * BSLACK;  // bucket t's size
  __syncthreads();
#pragma unroll
  for (int off = 1; off < NBUK; off <<= 1) {
    int x = (t >= off) ? bs[t - off] : 0;
    __syncthreads();
    bs[t] += x;
    __syncthreads();
  }
  int sz = bcur[b] - b * BSLACK;
  int colbase = bs[b] - sz;  // exclusive prefix of bucket sizes

  for (int i = t; i < BRANGE; i += 256) cnt[i] = 0;
  __syncthreads();

  int lo = b * BRANGE;
  int nnode = NN - lo;
  if (nnode > BRANGE) nnode = BRANGE;
  size_t e0 = (size_t)b * BSLACK;

  // Histogram dst within bucket (LDS atomics).
  for (int i = t; i < sz; i += 256) {
    long long pr = bpair[e0 + i];
    int d = (int)(unsigned)(pr >> 32);
    atomicAdd(&cnt[d - lo], 1);
  }
  __syncthreads();

  // Blocked exclusive scan of cnt[0..BRANGE): thread t owns indices 2t,2t+1.
  int i0 = 2 * t, i1 = 2 * t + 1;
  int v0 = (i0 < BRANGE) ? cnt[i0] : 0;
  int v1 = (i1 < BRANGE) ? cnt[i1] : 0;
  thsum[t] = v0 + v1;
  __syncthreads();
#pragma unroll
  for (int off = 1; off < 256; off <<= 1) {
    int x = (t >= off) ? thsum[t - off] : 0;
    __syncthreads();
    thsum[t] += x;
    __syncthreads();
  }
  int run = thsum[t] - (v0 + v1);  // exclusive prefix at i0
  if (i0 < nnode) {
    row_ptr[lo + i0] = colbase + run;
    dinv[lo + i0] = rsqrtf((float)(v0 + 1));  // +1 = self-loop
  }
  if (i0 < BRANGE) cnt[i0] = colbase + run;  // absolute cursor
  run += v0;
  if (i1 < nnode) {
    row_ptr[lo + i1] = colbase + run;
    dinv[lo + i1] = rsqrtf((float)(v1 + 1));
  }
  if (i1 < BRANGE) cnt[i1] = colbase + run;
  if (b == NBUK - 1 && t == 0) row_ptr[NN] = EE;
  __syncthreads();

  // Place: LDS cursor atomics, global writes within this block's window.
  for (int i = t; i < sz; i += 256) {
    long long pr = bpair[e0 + i];
    int d = (int)(unsigned)(pr >> 32);
    int s = (int)(unsigned)(pr & 0xffffffffLL);
    int pos = atomicAdd(&cnt[d - lo], 1);
    col[pos] = s;
  }
}

// G = dinv .* (X @ W).  128 nodes/block, thread = 4 nodes x 4 feats.
// xs padded to stride 36 floats to break power-of-2 LDS row conflicts.
template <int K>
__global__ __launch_bounds__(256) void k_gemm(const float* __restrict__ X,
                                              const float* __restrict__ W,
                                              const float* __restrict__ dinv,
                                              float* __restrict__ Gout) {
  __shared__ float Wl[K * HID];
  __shared__ float xs[128 * 36];
  int t = threadIdx.x;
  for (int i = t; i < K * HID; i += 256) Wl[i] = W[i];
  int node0 = blockIdx.x * 128;
  int ng = t >> 3, f4 = t & 7;
  float acc[4][4];
#pragma unroll
  for (int j = 0; j < 4; j++)
#pragma unroll
    for (int c = 0; c < 4; c++) acc[j][c] = 0.f;

  for (int kc = 0; kc < K; kc += 32) {
    __syncthreads();
#pragma unroll
    for (int j = 0; j < 4; j++) {
      int idx = t + 256 * j;  // 1024 float4 slots = 128 rows x 8
      int r = idx >> 3, c4 = idx & 7;
      int row = node0 + r;
      if (row >= NN) row = NN - 1;
      float4 v = *reinterpret_cast<const float4*>(&X[(size_t)row * K + kc + c4 * 4]);
      *reinterpret_cast<float4*>(&xs[r * 36 + c4 * 4]) = v;
    }
    __syncthreads();
#pragma unroll
    for (int k4 = 0; k4 < 8; k4++) {
      float4 xv[4];
#pragma unroll
      for (int j = 0; j < 4; j++)
        xv[j] = *reinterpret_cast<const float4*>(&xs[(ng * 4 + j) * 36 + k4 * 4]);
#pragma unroll
      for (int kk = 0; kk < 4; kk++) {
        float4 wv = *reinterpret_cast<const float4*>(&Wl[(kc + k4 * 4 + kk) * HID + f4 * 4]);
#pragma unroll
        for (int j = 0; j < 4; j++) {
          float xvj = (kk == 0) ? xv[j].x : (kk == 1) ? xv[j].y : (kk == 2) ? xv[j].z : xv[j].w;
          acc[j][0] += xvj * wv.x;
          acc[j][1] += xvj * wv.y;
          acc[j][2] += xvj * wv.z;
          acc[j][3] += xvj * wv.w;
        }
      }
    }
  }
#pragma unroll
  for (int j = 0; j < 4; j++) {
    int node = node0 + ng * 4 + j;
    if (node < NN) {
      float s = dinv[node];
      float4 o;
      o.x = acc[j][0] * s;
      o.y = acc[j][1] * s;
      o.z = acc[j][2] * s;
      o.w = acc[j][3] * s;
      *reinterpret_cast<float4*>(&Gout[(size_t)node * HID + f4 * 4]) = o;
    }
  }
}

// X'[n] = act(dinv[n] * (sum_{in-edges} G[src] + G[n]) + b).
// 16 lanes x float2 per node (4 nodes/wave, 16 nodes/block); 8x unrolled
// into 8 independent accumulators for 8 outstanding gathers per slot.
__global__ __launch_bounds__(256) void k_agg(const float* __restrict__ Gin,
                                             const int* __restrict__ col,
                                             const int* __restrict__ row_ptr,
                                             const float* __restrict__ dinv,
                                             const float* __restrict__ bias,
                                             float* __restrict__ Xout, int relu) {
  const float2* G2 = reinterpret_cast<const float2*>(Gin);
  int t = threadIdx.x;
  int h = t & 15;          // float2 index within row (feats 2h, 2h+1)
  int slot = t >> 4;       // 0..15 node slot within block
  int n = blockIdx.x * 16 + slot;
  int beg = row_ptr[n], end = row_ptr[n + 1];

  float2 a0 = G2[(size_t)n * 16 + h];  // self-loop term
  float2 a1 = {0.f, 0.f}, a2 = {0.f, 0.f}, a3 = {0.f, 0.f};
  float2 a4 = {0.f, 0.f}, a5 = {0.f, 0.f}, a6 = {0.f, 0.f}, a7 = {0.f, 0.f};

  int i = beg;
  for (; i + 8 <= end; i += 8) {
    int s0 = __builtin_nontemporal_load(&col[i + 0]);
    int s1 = __builtin_nontemporal_load(&col[i + 1]);
    int s2 = __builtin_nontemporal_load(&col[i + 2]);
    int s3 = __builtin_nontemporal_load(&col[i + 3]);
    int s4 = __builtin_nontemporal_load(&col[i + 4]);
    int s5 = __builtin_nontemporal_load(&col[i + 5]);
    int s6 = __builtin_nontemporal_load(&col[i + 6]);
    int s7 = __builtin_nontemporal_load(&col[i + 7]);
    float2 g0 = G2[(size_t)s0 * 16 + h];
    float2 g1 = G2[(size_t)s1 * 16 + h];
    float2 g2 = G2[(size_t)s2 * 16 + h];
    float2 g3 = G2[(size_t)s3 * 16 + h];
    float2 g4 = G2[(size_t)s4 * 16 + h];
    float2 g5 = G2[(size_t)s5 * 16 + h];
    float2 g6 = G2[(size_t)s6 * 16 + h];
    float2 g7 = G2[(size_t)s7 * 16 + h];
    a0.x += g0.x; a0.y += g0.y;
    a1.x += g1.x; a1.y += g1.y;
    a2.x += g2.x; a2.y += g2.y;
    a3.x += g3.x; a3.y += g3.y;
    a4.x += g4.x; a4.y += g4.y;
    a5.x += g5.x; a5.y += g5.y;
    a6.x += g6.x; a6.y += g6.y;
    a7.x += g7.x; a7.y += g7.y;
  }
  for (; i < end; i++) {
    int s = __builtin_nontemporal_load(&col[i]);
    float2 g = G2[(size_t)s * 16 + h];
    a0.x += g.x; a0.y += g.y;
  }
  a0.x += a1.x + a2.x + a3.x + a4.x + a5.x + a6.x + a7.x;
  a0.y += a1.y + a2.y + a3.y + a4.y + a5.y + a6.y + a7.y;

  float s = dinv[n];
  float2 b = reinterpret_cast<const float2*>(bias)[h];
  float2 v;
  v.x = s * a0.x + b.x;
  v.y = s * a0.y + b.y;
  if (relu) {
    v.x = fmaxf(v.x, 0.f);
    v.y = fmaxf(v.y, 0.f);
  }
  reinterpret_cast<float2*>(Xout)[(size_t)n * 16 + h] = v;
}

// Mean-pool: batch is sorted, so flush-on-graph-change keeps atomics rare.
__global__ __launch_bounds__(256) void k_pool(const float* __restrict__ X,
                                              const int* __restrict__ batch,
                                              float* __restrict__ sums,
                                              int* __restrict__ counts) {
  int t = threadIdx.x;
  int f = t & 31, slot = t >> 5;
  int base = blockIdx.x * 512;
  float acc = 0.f;
  int cnt = 0, cur = -1;
  for (int i = 0; i < 64; i++) {
    int n = base + slot + i * 8;
    if (n >= NN) break;
    int g = batch[n];
    if (g != cur) {
      if (cur >= 0) {
        atomicAdd(&sums[cur * HID + f], acc);
        if (f == 0) atomicAdd(&counts[cur], cnt);
      }
      cur = g;
      acc = 0.f;
      cnt = 0;
    }
    acc += X[(size_t)n * HID + f];
    cnt++;
  }
  if (cur >= 0) {
    atomicAdd(&sums[cur * HID + f], acc);
    if (f == 0) atomicAdd(&counts[cur], cnt);
  }
}

__global__ void k_fc(const float* __restrict__ sums, const int* __restrict__ counts,
                     const float* __restrict__ Wfc, const float* __restrict__ bfc,
                     float* __restrict__ out) {
  int idx = blockIdx.x * 256 + threadIdx.x;
  if (idx >= NGR * NC) return;
  int g = idx / NC, c = idx % NC;
  float inv = 1.f / fmaxf((float)counts[g], 1.f);
  float acc = bfc[c];
#pragma unroll
  for (int k = 0; k < HID; k++) acc += sums[g * HID + k] * inv * Wfc[k * NC + c];
  out[idx] = acc;
}

extern "C" void kernel_launch(void* const* d_in, const int* in_sizes, int n_in,
                              void* d_out, int out_size, void* d_ws, size_t ws_size,
                              hipStream_t stream) {
  (void)in_sizes; (void)n_in; (void)out_size; (void)ws_size;
  const float* x = (const float*)d_in[0];
  const int* ei = (const int*)d_in[1];
  const int* batch = (const int*)d_in[2];
  const float* W1 = (const float*)d_in[3];
  const float* b1 = (const float*)d_in[4];
  const float* W2 = (const float*)d_in[5];
  const float* b2 = (const float*)d_in[6];
  const float* W3 = (const float*)d_in[7];
  const float* b3 = (const float*)d_in[8];
  const float* Wfc = (const float*)d_in[9];
  const float* bfc = (const float*)d_in[10];
  float* out = (float*)d_out;

  char* ws = (char*)d_ws;
  size_t off = 0;
  auto alloc = [&](size_t bytes) -> void* {
    void* p = ws + off;
    off = (off + bytes + 255) & ~(size_t)255;
    return p;
  };
  float* dinv = (float*)alloc((size_t)NN * 4);
  int* row_ptr = (int*)alloc((size_t)(NN + 1) * 4);
  int* bcur = (int*)alloc(NBUK * 4);
  int* col = (int*)alloc((size_t)EE * 4);
  // Union region: bpair (CSR build only) overlaps Gbuf+Abuf (GEMM phase only).
  size_t bpair_bytes = (size_t)NBUK * BSLACK * 8;       // 27.4 MB
  size_t gbuf_bytes = (size_t)NN * HID * 4;             // 12.8 MB
  char* uni = (char*)alloc(bpair_bytes > 2 * gbuf_bytes ? bpair_bytes : 2 * gbuf_bytes);
  long long* bpair = (long long*)uni;
  float* Gbuf = (float*)uni;
  float* Abuf = (float*)(uni + gbuf_bytes);
  float* sums = (float*)alloc((size_t)NGR * HID * 4);
  int* counts = (int*)alloc((size_t)NGR * 4);

  hipMemsetAsync(sums, 0, (size_t)NGR * HID * 4, stream);
  hipMemsetAsync(counts, 0, (size_t)NGR * 4, stream);

  k_init<<<1, NBUK, 0, stream>>>(bcur);
  k_bucket<<<(EE + TILE - 1) / TILE, 256, 0, stream>>>(ei, bcur, bpair);  // 391 blocks
  k_place<<<NBUK, 256, 0, stream>>>(bpair, bcur, dinv, row_ptr, col);

  k_gemm<FIN><<<(NN + 127) / 128, 256, 0, stream>>>(x, W1, dinv, Gbuf);
  k_agg<<<NN / 16, 256, 0, stream>>>(Gbuf, col, row_ptr, dinv, b1, Abuf, 1);
  k_gemm<HID><<<(NN + 127) / 128, 256, 0, stream>>>(Abuf, W2, dinv, Gbuf);
  k_agg<<<NN / 16, 256, 0, stream>>>(Gbuf, col, row_ptr, dinv, b2, Abuf, 1);
  k_gemm<HID><<<(NN + 127) / 128, 256, 0, stream>>>(Abuf, W3, dinv, Gbuf);
  k_agg<<<NN / 16, 256, 0, stream>>>(Gbuf, col, row_ptr, dinv, b3, Abuf, 0);

  k_pool<<<(NN + 511) / 512, 256, 0, stream>>>(Abuf, batch, sums, counts);
  k_fc<<<(NGR * NC + 255) / 256, 256, 0, stream>>>(sums, counts, Wfc, bfc, out);
}